// Round 1
// baseline (7689.395 us; speedup 1.0000x reference)
//
#include <hip/hip_runtime.h>
#include <hip/hip_bf16.h>

#define IMG  112
#define CCH  256
#define NHH  8
#define HD   32
#define NTOK 49
#define QK_SCALE 0.17677669529663687f  // 1/sqrt(32)

// One block = one window. 256 threads = 8 groups of 32 lanes.
// Lane j = head-dim column (0..31); group g owns rows m = g + 8*r.
__global__ __launch_bounds__(256)
void swin_fused_kernel(const float* __restrict__ xin,    // (B,112,112,256)
                       const float* __restrict__ qkvw,   // (768,256)
                       const float* __restrict__ qkvb,   // (768)
                       const float* __restrict__ projw,  // (256,256)
                       const float* __restrict__ projb,  // (256)
                       const float* __restrict__ rpb,    // (1,8,49,49)
                       float* __restrict__ yout)         // (B,112,112,256)
{
    __shared__ float sQ[NTOK][HD];     // q (scaled, +bias)
    __shared__ float sKT[HD][52];      // k transposed, padded for float4 + banks
    __shared__ float sV[NTOK][HD];
    __shared__ float sS[NTOK][52];     // scores / exp(scores)
    __shared__ float sO[NTOK][HD];     // per-head attention output
    __shared__ float sRc[NTOK];        // 1/rowsum
    __shared__ int   sCat[NTOK];       // shift-mask category per token

    const int tid = threadIdx.x;
    const int j   = tid & 31;          // column within head
    const int g   = tid >> 5;          // row group 0..7
    const int blk = blockIdx.x;
    const int b   = blk >> 8;
    const int wy  = (blk >> 4) & 15;
    const int wx  = blk & 15;
    const int nrows = (g == 0) ? 7 : 6;   // rows m = g+8r, m<=48

    // Shift-mask categories: regions [0,105),[105,109),[109,112) per axis.
    if (tid < NTOK) {
        int rr = tid / 7, cc = tid % 7;
        int hy = wy * 7 + rr, hx = wx * 7 + cc;
        int rcat = (hy < 105) ? 0 : ((hy < 109) ? 1 : 2);
        int ccat = (hx < 105) ? 0 : ((hx < 109) ? 1 : 2);
        sCat[tid] = rcat * 3 + ccat;
    }

    // Per-thread source row base pointers (cyclic shift by +3 folded in).
    const float* xbase[7];
    int mrow[7];
#pragma unroll
    for (int r = 0; r < 7; ++r) {
        int m = g + 8 * r; if (m > 48) m = 48;   // clamp (guarded later)
        mrow[r] = m;
        int hy = wy * 7 + m / 7 + 3; if (hy >= IMG) hy -= IMG;
        int hx = wx * 7 + m % 7 + 3; if (hx >= IMG) hx -= IMG;
        xbase[r] = xin + (((size_t)b * IMG + hy) * IMG + hx) * CCH;
    }

    // Final output accumulator: thread owns column `tid` for all 49 rows.
    float accO[NTOK];
#pragma unroll
    for (int n = 0; n < NTOK; ++n) accO[n] = 0.f;

    __syncthreads();   // sCat ready

    for (int h = 0; h < NHH; ++h) {
        // ---------- phase 1: q,k,v for this head (global -> regs -> LDS) ----
        float aq[7], ak[7], av[7];
#pragma unroll
        for (int r = 0; r < 7; ++r) { aq[r] = 0.f; ak[r] = 0.f; av[r] = 0.f; }
        const float* wq = qkvw + (size_t)(h * HD + j) * CCH;
        const float* wk = wq + (size_t)256 * CCH;
        const float* wv = wk + (size_t)256 * CCH;
        for (int kc = 0; kc < CCH; kc += 4) {
            const float4 wq4 = *(const float4*)(wq + kc);
            const float4 wk4 = *(const float4*)(wk + kc);
            const float4 wv4 = *(const float4*)(wv + kc);
#pragma unroll
            for (int r = 0; r < 7; ++r) {
                if (r < nrows) {
                    const float4 xv = *(const float4*)(xbase[r] + kc);
                    aq[r] += xv.x * wq4.x + xv.y * wq4.y + xv.z * wq4.z + xv.w * wq4.w;
                    ak[r] += xv.x * wk4.x + xv.y * wk4.y + xv.z * wk4.z + xv.w * wk4.w;
                    av[r] += xv.x * wv4.x + xv.y * wv4.y + xv.z * wv4.z + xv.w * wv4.w;
                }
            }
        }
        {
            const float qb = qkvb[h * HD + j];
            const float kb = qkvb[256 + h * HD + j];
            const float vb = qkvb[512 + h * HD + j];
#pragma unroll
            for (int r = 0; r < 7; ++r) {
                if (r < nrows) {
                    const int m = mrow[r];
                    sQ[m][j]  = (aq[r] + qb) * QK_SCALE;
                    sKT[j][m] = ak[r] + kb;
                    sV[m][j]  = av[r] + vb;
                }
            }
        }
        __syncthreads();   // A

        // ---------- phase 2: scores S = qk^T + rpb + mask ----
        for (int qi = tid; qi < 49 * 13; qi += 256) {
            const int n  = qi / 13;
            const int mq = (qi % 13) * 4;
            float a0 = 0.f, a1 = 0.f, a2 = 0.f, a3 = 0.f;
            for (int kk = 0; kk < HD; ++kk) {
                const float qv = sQ[n][kk];
                const float4 kv = *(const float4*)&sKT[kk][mq];
                a0 += qv * kv.x; a1 += qv * kv.y; a2 += qv * kv.z; a3 += qv * kv.w;
            }
            const int catn = sCat[n];
            const float acc4[4] = { a0, a1, a2, a3 };
#pragma unroll
            for (int e = 0; e < 4; ++e) {
                const int mm = mq + e;
                if (mm < NTOK) {
                    float s = acc4[e] + rpb[((size_t)h * NTOK + n) * NTOK + mm];
                    if (sCat[mm] != catn) s -= 100.f;
                    sS[n][mm] = s;
                }
            }
        }
        __syncthreads();   // B

        // ---------- phase 3: row softmax (normalization deferred to PV) ----
        if (tid < NTOK) {
            const int n = tid;
            float mx = -1e30f;
            for (int mm = 0; mm < NTOK; ++mm) mx = fmaxf(mx, sS[n][mm]);
            float sum = 0.f;
            for (int mm = 0; mm < NTOK; ++mm) {
                const float e = __expf(sS[n][mm] - mx);
                sS[n][mm] = e;
                sum += e;
            }
            sRc[n] = 1.f / sum;
        }
        __syncthreads();   // C

        // ---------- phase 4: O = softmax(S) @ V ----
        {
            float ap[7];
#pragma unroll
            for (int r = 0; r < 7; ++r) ap[r] = 0.f;
            for (int mm = 0; mm < NTOK; ++mm) {
                const float vv = sV[mm][j];
#pragma unroll
                for (int r = 0; r < 7; ++r)
                    if (r < nrows) ap[r] += sS[mrow[r]][mm] * vv;
            }
#pragma unroll
            for (int r = 0; r < 7; ++r)
                if (r < nrows) sO[mrow[r]][j] = ap[r] * sRc[mrow[r]];
        }
        __syncthreads();   // D

        // ---------- phase 5: out[:, tid] += O_h @ projW[tid, h*32:(h+1)*32] ----
        {
            float4 pw[8];
            const float* pwp = projw + (size_t)tid * CCH + h * HD;
#pragma unroll
            for (int q4 = 0; q4 < 8; ++q4) pw[q4] = *(const float4*)(pwp + 4 * q4);
#pragma unroll
            for (int n = 0; n < NTOK; ++n) {
                float s = 0.f;
#pragma unroll
                for (int q4 = 0; q4 < 8; ++q4) {
                    const float4 o4 = *(const float4*)&sO[n][4 * q4];
                    s += o4.x * pw[q4].x + o4.y * pw[q4].y + o4.z * pw[q4].z + o4.w * pw[q4].w;
                }
                accO[n] += s;
            }
        }
        // No trailing barrier needed: next head's phase-1 LDS stores touch
        // sQ/sKT/sV (disjoint from sO), and phase-4's sO writes sit behind
        // three barriers of the next iteration.
    }

    // ---------- epilogue: +proj_bias, un-partition, reverse shift ----------
    const float pb = projb[tid];
#pragma unroll
    for (int n = 0; n < NTOK; ++n) {
        int hy = wy * 7 + n / 7 + 3; if (hy >= IMG) hy -= IMG;
        int hx = wx * 7 + n % 7 + 3; if (hx >= IMG) hx -= IMG;
        yout[(((size_t)b * IMG + hy) * IMG + hx) * CCH + tid] = accO[n] + pb;
    }
}

extern "C" void kernel_launch(void* const* d_in, const int* in_sizes, int n_in,
                              void* d_out, int out_size, void* d_ws, size_t ws_size,
                              hipStream_t stream) {
    const float* xin   = (const float*)d_in[0];
    const float* qkvw  = (const float*)d_in[1];
    const float* qkvb  = (const float*)d_in[2];
    const float* projw = (const float*)d_in[3];
    const float* projb = (const float*)d_in[4];
    const float* rpb   = (const float*)d_in[5];
    float* yout = (float*)d_out;

    const int B = in_sizes[0] / (IMG * IMG * CCH);   // 16
    dim3 grid(B * 16 * 16), block(256);
    hipLaunchKernelGGL(swin_fused_kernel, grid, block, 0, stream,
                       xin, qkvw, qkvb, projw, projb, rpb, yout);
}

// Round 2
// 1341.123 us; speedup vs baseline: 5.7335x; 5.7335x over previous
//
#include <hip/hip_runtime.h>
#include <hip/hip_bf16.h>

#define IMG  112
#define CCH  256
#define NHH  8
#define NTOK 49
#define QK_SCALE 0.17677669529663687f  // 1/sqrt(32)

typedef __attribute__((ext_vector_type(8))) short bf16x8;   // MFMA A/B frag (4 VGPRs)
typedef __attribute__((ext_vector_type(4))) short s16x4;    // 8B LDS store
typedef __attribute__((ext_vector_type(4))) float f32x4;    // MFMA C/D frag

__device__ __forceinline__ short f2bf(float f) {            // fp32 -> bf16 (RNE)
    union { float f; unsigned u; } v; v.f = f;
    unsigned r = (v.u + 0x7FFFu + ((v.u >> 16) & 1u)) >> 16;
    return (short)r;
}

// ---- pre-kernel: fp32 weights -> bf16 in workspace (runs every launch) ----
__global__ __launch_bounds__(256)
void cvt_weights(const float* __restrict__ qkvw, const float* __restrict__ projw,
                 short* __restrict__ wsb) {
    int i = blockIdx.x * 256 + threadIdx.x;       // grid sized exactly 262144
    if (i < 196608) wsb[i] = f2bf(qkvw[i]);
    else            wsb[i] = f2bf(projw[i - 196608]);
}

// One block = one window. 4 waves; wave w owns query-token rows 16w..16w+15.
__global__ __launch_bounds__(256, 2)
void swin_mfma(const float* __restrict__ xin,    // (B,112,112,256) f32
               const short* __restrict__ wqkv,   // (768,256) bf16  [n][k]
               const float* __restrict__ qkvb,   // (768)
               const short* __restrict__ wp,     // (256,256) bf16  [n][k]
               const float* __restrict__ projb,  // (256)
               const float* __restrict__ rpb,    // (8,49,49) f32
               float* __restrict__ yout)         // (B,112,112,256) f32
{
    __shared__ short sX[64 * 256];   // x window bf16, XOR-swizzled 16B granules
    __shared__ short sQ[64 * 40];    // q bf16 [token][d], scaled (+pad)
    __shared__ short sK[64 * 40];    // k bf16 [token][d]
    __shared__ short sVt[32 * 72];   // v bf16 TRANSPOSED [d][token]
    __shared__ short sP[64 * 72];    // softmax probs bf16 [token][kv] (kv>=49 zero)
    __shared__ short sO[64 * 40];    // per-head attn out bf16 [token][d]
    __shared__ int   sCat[64];       // shift-mask category per token
    __shared__ int   sRowOff[64];    // output element offset per token (rev-shifted)

    const int tid  = threadIdx.x;
    const int lane = tid & 63;
    const int w    = tid >> 6;          // wave id == M-tile id
    const int l15  = lane & 15;
    const int l4   = lane >> 4;         // 0..3
    const int blk  = blockIdx.x;
    const int b    = blk >> 8;
    const int wy   = (blk >> 4) & 15;
    const int wx   = blk & 15;

    // ---------------- stage x -> bf16 -> LDS (swizzled) ----------------
    for (int i = tid; i < NTOK * 64; i += 256) {          // i indexes float4 chunks
        const int row = i >> 6, c4 = i & 63;
        const int r7 = (row * 37) >> 8, c7 = row - r7 * 7;
        int hy = wy * 7 + r7 + 3; if (hy >= IMG) hy -= IMG;
        int hx = wx * 7 + c7 + 3; if (hx >= IMG) hx -= IMG;
        const float4 v = *(const float4*)(xin + ((((size_t)b * IMG + hy) * IMG + hx) << 8) + c4 * 4);
        s16x4 pk = { f2bf(v.x), f2bf(v.y), f2bf(v.z), f2bf(v.w) };
        const int g = c4 >> 1;                            // 16B granule index 0..31
        const int off = row * 256 + ((g ^ (row & 7)) << 3) + ((c4 & 1) << 2);
        *(s16x4*)&sX[off] = pk;
    }
    for (int i = tid; i < 15 * 64; i += 256) {            // zero rows 49..63
        s16x4 z = { 0, 0, 0, 0 };
        *(s16x4*)&sX[NTOK * 256 + i * 4] = z;
    }
    if (tid < 64) {
        const int t = tid < 48 ? tid : 48;
        const int r7 = (t * 37) >> 8, c7 = t - r7 * 7;
        const int hy = wy * 7 + r7, hx = wx * 7 + c7;     // rolled-grid coords for mask
        const int rc = (hy < 105) ? 0 : ((hy < 109) ? 1 : 2);
        const int cc = (hx < 105) ? 0 : ((hx < 109) ? 1 : 2);
        sCat[tid] = rc * 3 + cc;
        int hy2 = hy + 3; if (hy2 >= IMG) hy2 -= IMG;     // reverse-shift output coords
        int hx2 = hx + 3; if (hx2 >= IMG) hx2 -= IMG;
        sRowOff[tid] = ((b * IMG + hy2) * IMG + hx2) << 8;
    }
    __syncthreads();

    // persistent proj accumulators: wave w rows, all 256 out channels
    f32x4 accP[16];
#pragma unroll
    for (int i = 0; i < 16; ++i) accP[i] = (f32x4){0.f, 0.f, 0.f, 0.f};

    const int rowA = w * 16 + l15;      // A-frag row (token) for this wave/lane
    const int tokW = w * 16 + l4 * 4;   // C-frag row base (token) for this lane

    for (int h = 0; h < NHH; ++h) {
        // ---------- QKV GEMM: (49x256) @ (256x96) for this head ----------
        f32x4 acc6[6];
#pragma unroll
        for (int j = 0; j < 6; ++j) acc6[j] = (f32x4){0.f, 0.f, 0.f, 0.f};
        const int nb0 = h * 32;
        const int nbase[6] = { nb0, nb0 + 16, 256 + nb0, 256 + nb0 + 16, 512 + nb0, 512 + nb0 + 16 };
#pragma unroll
        for (int kt = 0; kt < 8; ++kt) {
            const int g = kt * 4 + l4;
            const bf16x8 a = *(const bf16x8*)&sX[rowA * 256 + ((g ^ (rowA & 7)) << 3)];
#pragma unroll
            for (int j = 0; j < 6; ++j) {
                const bf16x8 bf = *(const bf16x8*)&wqkv[(nbase[j] + l15) * 256 + kt * 32 + l4 * 8];
                acc6[j] = __builtin_amdgcn_mfma_f32_16x16x32_bf16(a, bf, acc6[j], 0, 0, 0);
            }
        }
        __syncthreads();   // all waves done reading prev head's sQ/sK/sVt
        // epilogue: +bias, write q (scaled), k, v (transposed)
#pragma unroll
        for (int j = 0; j < 6; ++j) {
            const float bias = qkvb[nbase[j] + l15];
#pragma unroll
            for (int r = 0; r < 4; ++r) {
                const float vv = acc6[j][r] + bias;
                const int tok = tokW + r;
                if (j < 2)       sQ[tok * 40 + j * 16 + l15]         = f2bf(vv * QK_SCALE);
                else if (j < 4)  sK[tok * 40 + (j - 2) * 16 + l15]   = f2bf(vv);
                else             sVt[((j - 4) * 16 + l15) * 72 + tok] = f2bf(vv);
            }
        }
        __syncthreads();   // q/k/v visible to all waves

        // ---------- S = Q @ K^T : stays in C-frags of this wave ----------
        f32x4 accS[4];
        {
            const bf16x8 qa = *(const bf16x8*)&sQ[rowA * 40 + l4 * 8];
#pragma unroll
            for (int nt = 0; nt < 4; ++nt) {
                const bf16x8 kb = *(const bf16x8*)&sK[(nt * 16 + l15) * 40 + l4 * 8];
                f32x4 z = (f32x4){0.f, 0.f, 0.f, 0.f};
                accS[nt] = __builtin_amdgcn_mfma_f32_16x16x32_bf16(qa, kb, z, 0, 0, 0);
            }
        }

        // ---------- softmax (in-register, 16-lane shfl reduce) ----------
        const float* rpbh = rpb + h * NTOK * NTOK;
        float rsc[4];
#pragma unroll
        for (int r = 0; r < 4; ++r) {
            const int row  = tokW + r;
            const int rowc = row < 48 ? row : 48;
            const int catr = sCat[rowc];
            float sv[4];
            float mx = -1e30f;
#pragma unroll
            for (int nt = 0; nt < 4; ++nt) {
                const int col  = nt * 16 + l15;
                const int colc = col < 48 ? col : 48;
                float s = accS[nt][r] + rpbh[rowc * NTOK + colc];
                if (sCat[colc] != catr) s -= 100.f;
                sv[nt] = s;
                if (col < NTOK) mx = fmaxf(mx, s);
            }
            mx = fmaxf(mx, __shfl_xor(mx, 1));
            mx = fmaxf(mx, __shfl_xor(mx, 2));
            mx = fmaxf(mx, __shfl_xor(mx, 4));
            mx = fmaxf(mx, __shfl_xor(mx, 8));
            float sum = 0.f;
#pragma unroll
            for (int nt = 0; nt < 4; ++nt) {
                const int col = nt * 16 + l15;
                const float p = (col < NTOK) ? __expf(sv[nt] - mx) : 0.f;
                sum += p;
                sP[row * 72 + col] = f2bf(p);     // own-wave rows; same-wave DS in order
            }
            sum += __shfl_xor(sum, 1);
            sum += __shfl_xor(sum, 2);
            sum += __shfl_xor(sum, 4);
            sum += __shfl_xor(sum, 8);
            rsc[r] = (sum > 0.f) ? 1.f / sum : 0.f;
        }

        // ---------- O = P @ V ----------
        f32x4 accO[2];
        accO[0] = (f32x4){0.f, 0.f, 0.f, 0.f};
        accO[1] = (f32x4){0.f, 0.f, 0.f, 0.f};
#pragma unroll
        for (int kt = 0; kt < 2; ++kt) {
            const bf16x8 pa = *(const bf16x8*)&sP[rowA * 72 + kt * 32 + l4 * 8];
#pragma unroll
            for (int nt = 0; nt < 2; ++nt) {
                const bf16x8 vb = *(const bf16x8*)&sVt[(nt * 16 + l15) * 72 + kt * 32 + l4 * 8];
                accO[nt] = __builtin_amdgcn_mfma_f32_16x16x32_bf16(pa, vb, accO[nt], 0, 0, 0);
            }
        }
#pragma unroll
        for (int nt = 0; nt < 2; ++nt)
#pragma unroll
            for (int r = 0; r < 4; ++r)
                sO[(tokW + r) * 40 + nt * 16 + l15] = f2bf(accO[nt][r] * rsc[r]);

        // ---------- proj: accP += O_h @ Wp[:, h*32:(h+1)*32]^T ----------
        {
            const bf16x8 oa = *(const bf16x8*)&sO[rowA * 40 + l4 * 8];
#pragma unroll
            for (int nt = 0; nt < 16; ++nt) {
                const bf16x8 wb = *(const bf16x8*)&wp[(nt * 16 + l15) * 256 + h * 32 + l4 * 8];
                accP[nt] = __builtin_amdgcn_mfma_f32_16x16x32_bf16(oa, wb, accP[nt], 0, 0, 0);
            }
        }
    }

    // ---------------- epilogue: +bias, gated reverse-shift store ----------------
#pragma unroll
    for (int nt = 0; nt < 16; ++nt) {
        const int c = nt * 16 + l15;
        const float pb = projb[c];
#pragma unroll
        for (int r = 0; r < 4; ++r) {
            const int tok = tokW + r;
            if (tok < NTOK)
                yout[(size_t)sRowOff[tok] + c] = accP[nt][r] + pb;
        }
    }
}

extern "C" void kernel_launch(void* const* d_in, const int* in_sizes, int n_in,
                              void* d_out, int out_size, void* d_ws, size_t ws_size,
                              hipStream_t stream) {
    const float* xin   = (const float*)d_in[0];
    const float* qkvw  = (const float*)d_in[1];
    const float* qkvb  = (const float*)d_in[2];
    const float* projw = (const float*)d_in[3];
    const float* projb = (const float*)d_in[4];
    const float* rpb   = (const float*)d_in[5];
    float* yout = (float*)d_out;
    short* wsb  = (short*)d_ws;     // 262144 bf16 = 512 KiB

    hipLaunchKernelGGL(cvt_weights, dim3(1024), dim3(256), 0, stream, qkvw, projw, wsb);

    const int B = in_sizes[0] / (IMG * IMG * CCH);   // 16
    hipLaunchKernelGGL(swin_mfma, dim3(B * 256), dim3(256), 0, stream,
                       xin, wsb, qkvb, wsb + 196608, projb, rpb, yout);
}